// Round 4
// baseline (516.635 us; speedup 1.0000x reference)
//
#include <hip/hip_runtime.h>
#include <hip/hip_bf16.h>

typedef __bf16 bf16x8 __attribute__((ext_vector_type(8)));
typedef float f32x4 __attribute__((ext_vector_type(4)));

#define DEV static __device__ __forceinline__

DEV unsigned short f2b(float f) {
  return __builtin_bit_cast(unsigned short, __float2bfloat16(f));
}
DEV unsigned pk2(float a, float b) {
  return (unsigned)f2b(a) | ((unsigned)f2b(b) << 16);
}
DEV void unpack2(unsigned u, float& lo, float& hi) {
  lo = __uint_as_float(u << 16);
  hi = __uint_as_float(u & 0xffff0000u);
}
// tanh-form gelu: h*e/(e+1), e = exp(2*sqrt(2/pi)*(h+0.044715h^3)).
// Written as h - h*rcp(e+1): exact at both saturation ends (e->inf => h, e->0 => 0).
DEV float gelu_fast(float h) {
  float u = h * (1.5957691216f + 0.0713554f * h * h);
  float e = __expf(u);
  float r = __builtin_amdgcn_rcpf(e + 1.f);
  return h - h * r;
}

// ---- weight packing: src [k][n] fp32 -> fragment-native bf16 layout ----
// dst[((ntile*KC + kc)*512) + nl*32 + kgl] for n = ntile*16+nl, k = kc*32+kgl.
// A wave's (ntile,kc) fragment load = 64 lanes x 16B = contiguous 1KB.
// ws element offsets: wq@0 (110592) wo@110592 (36864) wf1@147456 (73728) wf2@221184 (73728)
__global__ void pack_weights(const float* __restrict__ wq,
                             const float* __restrict__ wo,
                             const float* __restrict__ wf1,
                             const float* __restrict__ wf2,
                             unsigned short* __restrict__ ws) {
  int i = blockIdx.x * 256 + threadIdx.x;  // grid covers exactly 294912
  const float* src; int j, N, KC;
  if (i < 110592)      { j = i;          src = wq;  N = 576; KC = 6; }
  else if (i < 147456) { j = i - 110592; src = wo;  N = 192; KC = 6; }
  else if (i < 221184) { j = i - 147456; src = wf1; N = 384; KC = 6; }
  else                 { j = i - 221184; src = wf2; N = 192; KC = 12; }
  int tk = j >> 9, r = j & 511;
  int nt = tk / KC, kc = tk % KC;
  int n = nt * 16 + (r >> 5), k = kc * 32 + (r & 31);
  ws[i] = f2b(src[k * N + n]);
}

// GEMM stage, swapped operands: mfma(b_frag, a_frag).
// Thread (lr,kg): C[token = m*16+lr][n = (nt0+nt)*16 + kg*4 .. +3].
// A: LDS bf16 [32 x K] stride astride. Bp: packed global bf16 (layout above).
// B fragments double-buffered: nt+1's loads issue before nt's MFMAs.
template<int NT, int KC, typename EPI>
DEV void gemm_stage(const unsigned short* As, int astride,
                    const unsigned short* Bp, int nt0, int KCtot,
                    int lr, int kg, EPI epi) {
  bf16x8 af[2][KC];
  #pragma unroll
  for (int m = 0; m < 2; ++m)
    #pragma unroll
    for (int kc = 0; kc < KC; ++kc)
      af[m][kc] = *(const bf16x8*)(As + (m * 16 + lr) * astride + kc * 32 + kg * 8);
  const unsigned short* bb = Bp + lr * 32 + kg * 8;
  bf16x8 bbuf[2][KC];
  #pragma unroll
  for (int kc = 0; kc < KC; ++kc)
    bbuf[0][kc] = *(const bf16x8*)(bb + (size_t)(nt0 * KCtot + kc) * 512);
  #pragma unroll
  for (int nt = 0; nt < NT; ++nt) {
    if (nt + 1 < NT) {
      #pragma unroll
      for (int kc = 0; kc < KC; ++kc)
        bbuf[(nt + 1) & 1][kc] =
            *(const bf16x8*)(bb + (size_t)((nt0 + nt + 1) * KCtot + kc) * 512);
    }
    f32x4 acc[2] = {};
    #pragma unroll
    for (int kc = 0; kc < KC; ++kc)
      #pragma unroll
      for (int m = 0; m < 2; ++m)
        acc[m] = __builtin_amdgcn_mfma_f32_16x16x32_bf16(bbuf[nt & 1][kc], af[m][kc], acc[m], 0, 0, 0);
    epi(nt, acc);
  }
}

// LayerNorm over 32 rows: src = x (global, row stride 192) [+ A (LDS bf16, stride 392, col off 192)].
// dst = LDS bf16 stride 200. thread t: row = t>>3, eighth = t&7 (24 elems).
// Two-pass variance (matches reference mean((x-mu)^2) ordering).
template<bool ADD_A>
DEV void layernorm_pass(const float* __restrict__ xg, const unsigned short* Abuf,
                        unsigned short* dst,
                        const float* __restrict__ gg, const float* __restrict__ bb,
                        int t) {
  int r = t >> 3, q = t & 7;
  float vals[24];
  float s = 0.f;
  #pragma unroll
  for (int j = 0; j < 6; ++j) {
    float4 v = *(const float4*)(xg + (size_t)r * 192 + q * 24 + j * 4);
    if (ADD_A) {
      uint2 a2 = *(const uint2*)(Abuf + r * 392 + 192 + q * 24 + j * 4);
      float a0, a1, a2f, a3;
      unpack2(a2.x, a0, a1); unpack2(a2.y, a2f, a3);
      v.x += a0; v.y += a1; v.z += a2f; v.w += a3;
    }
    vals[j*4+0] = v.x; vals[j*4+1] = v.y; vals[j*4+2] = v.z; vals[j*4+3] = v.w;
    s += v.x + v.y + v.z + v.w;
  }
  s += __shfl_xor(s, 1); s += __shfl_xor(s, 2); s += __shfl_xor(s, 4);
  float mu = s * (1.f / 192.f);
  float ss = 0.f;
  #pragma unroll
  for (int i = 0; i < 24; ++i) { float d = vals[i] - mu; ss += d * d; }
  ss += __shfl_xor(ss, 1); ss += __shfl_xor(ss, 2); ss += __shfl_xor(ss, 4);
  float rstd = rsqrtf(ss * (1.f / 192.f) + 1e-5f);
  #pragma unroll
  for (int j = 0; j < 6; ++j) {
    int c = q * 24 + j * 4;
    float4 g4 = *(const float4*)(gg + c);
    float4 b4 = *(const float4*)(bb + c);
    uint2 u;
    u.x = pk2((vals[j*4+0] - mu) * rstd * g4.x + b4.x,
              (vals[j*4+1] - mu) * rstd * g4.y + b4.y);
    u.y = pk2((vals[j*4+2] - mu) * rstd * g4.z + b4.z,
              (vals[j*4+3] - mu) * rstd * g4.w + b4.w);
    *(uint2*)(dst + r * 200 + c) = u;
  }
}

// Fused transformer block: 4 batches (32 rows) per workgroup, 256 threads (4 waves).
// LDS: r1 bf16 32x200 (12800B: normed1 -> attnO -> normed2)
//      r2 bf16 32x392 (25088B): [Q 0..192 | K 192..384] -> [V 0..192 | A 192..384] -> h1 0..384
// total 37888B -> 4 blocks/CU (16 waves/CU). A also kept per-thread as packed bf16 regs for G4.
__global__ __launch_bounds__(256, 4)
void fused_block(const float* __restrict__ x,
                 const float* __restrict__ g1, const float* __restrict__ b1,
                 const float* __restrict__ g2, const float* __restrict__ b2,
                 const float* __restrict__ b_out, const float* __restrict__ b_f1,
                 const float* __restrict__ b_f2,
                 const unsigned short* __restrict__ wq_t,
                 const unsigned short* __restrict__ wo_t,
                 const unsigned short* __restrict__ wf1_t,
                 const unsigned short* __restrict__ wf2_t,
                 float* __restrict__ out)
{
  __shared__ __align__(16) unsigned short r1[32 * 200];
  __shared__ __align__(16) unsigned short r2[32 * 392];

  const int t = threadIdx.x;
  const int wave = t >> 6;
  const int lane = t & 63;
  const int lr = lane & 15;
  const int kg = lane >> 4;
  const int token0 = blockIdx.x * 32;
  const float* xg = x + (size_t)token0 * 192;
  float* og = out + (size_t)token0 * 192;

  // LN1: x (global) -> r1 (normed1, bf16)
  layernorm_pass<false>(xg, nullptr, r1, g1, b1, t);
  __syncthreads();

  // G1a: Q,K = normed1 @ w_qkv[:, :384]  (24 nt, wave owns 6) -> r2 stride 392
  gemm_stage<6, 6>(r1, 200, wq_t, wave * 6, 6, lr, kg,
    [&](int nt, f32x4 (&acc)[2]) {
      int n0 = (wave * 6 + nt) * 16 + kg * 4;
      #pragma unroll
      for (int m = 0; m < 2; ++m) {
        uint2 u; u.x = pk2(acc[m][0], acc[m][1]); u.y = pk2(acc[m][2], acc[m][3]);
        *(uint2*)(r2 + (m * 16 + lr) * 392 + n0) = u;
      }
    });
  __syncthreads();

  // attention scores: 16 (batch,head) groups x 8 q-rows x 2 d-halves.
  const int ag = t >> 4, aqi = (t >> 1) & 7, ahalf = t & 1;
  const int abl = ag >> 2, ah = ag & 3;
  const int aqrow = abl * 8 + aqi;
  const int ad0 = ahalf * 24;
  float p[8];
  {
    float qv[24];
    const uint4* qp = (const uint4*)(r2 + aqrow * 392 + ah * 48 + ad0);
    #pragma unroll
    for (int u = 0; u < 3; ++u) {
      uint4 w4 = qp[u];
      unpack2(w4.x, qv[u*8+0], qv[u*8+1]);
      unpack2(w4.y, qv[u*8+2], qv[u*8+3]);
      unpack2(w4.z, qv[u*8+4], qv[u*8+5]);
      unpack2(w4.w, qv[u*8+6], qv[u*8+7]);
    }
    #pragma unroll
    for (int j = 0; j < 8; ++j) {
      const uint4* kp = (const uint4*)(r2 + (abl * 8 + j) * 392 + 192 + ah * 48 + ad0);
      float d = 0.f;
      #pragma unroll
      for (int u = 0; u < 3; ++u) {
        uint4 w4 = kp[u];
        float lo, hi;
        unpack2(w4.x, lo, hi); d = fmaf(lo, qv[u*8+0], d); d = fmaf(hi, qv[u*8+1], d);
        unpack2(w4.y, lo, hi); d = fmaf(lo, qv[u*8+2], d); d = fmaf(hi, qv[u*8+3], d);
        unpack2(w4.z, lo, hi); d = fmaf(lo, qv[u*8+4], d); d = fmaf(hi, qv[u*8+5], d);
        unpack2(w4.w, lo, hi); d = fmaf(lo, qv[u*8+6], d); d = fmaf(hi, qv[u*8+7], d);
      }
      d += __shfl_xor(d, 1);             // combine the two d-halves
      p[j] = d * 0.14433756729740643f;   // 1/sqrt(48)
    }
    float mx = p[0];
    #pragma unroll
    for (int j = 1; j < 8; ++j) mx = fmaxf(mx, p[j]);
    float sum = 0.f;
    #pragma unroll
    for (int j = 0; j < 8; ++j) { p[j] = __expf(p[j] - mx); sum += p[j]; }
    float inv = 1.f / sum;
    #pragma unroll
    for (int j = 0; j < 8; ++j) p[j] *= inv;
  }
  __syncthreads();   // all Q/K reads done before V overwrites Q

  // G1b: V = normed1 @ w_qkv[:, 384:]  (nt 24..35, wave owns 3) -> r2 cols 0..191
  gemm_stage<3, 6>(r1, 200, wq_t, 24 + wave * 3, 6, lr, kg,
    [&](int nt, f32x4 (&acc)[2]) {
      int n0 = (wave * 3 + nt) * 16 + kg * 4;
      #pragma unroll
      for (int m = 0; m < 2; ++m) {
        uint2 u; u.x = pk2(acc[m][0], acc[m][1]); u.y = pk2(acc[m][2], acc[m][3]);
        *(uint2*)(r2 + (m * 16 + lr) * 392 + n0) = u;
      }
    });
  __syncthreads();

  // PV: O[q][d] = sum_j p[j] V[j][d]  -> r1 (overwrites normed1)
  {
    float oa[24];
    #pragma unroll
    for (int e = 0; e < 24; ++e) oa[e] = 0.f;
    #pragma unroll
    for (int j = 0; j < 8; ++j) {
      float pj = p[j];
      const uint4* vp = (const uint4*)(r2 + (abl * 8 + j) * 392 + ah * 48 + ad0);
      #pragma unroll
      for (int u = 0; u < 3; ++u) {
        uint4 w4 = vp[u];
        float lo, hi;
        unpack2(w4.x, lo, hi); oa[u*8+0] = fmaf(pj, lo, oa[u*8+0]); oa[u*8+1] = fmaf(pj, hi, oa[u*8+1]);
        unpack2(w4.y, lo, hi); oa[u*8+2] = fmaf(pj, lo, oa[u*8+2]); oa[u*8+3] = fmaf(pj, hi, oa[u*8+3]);
        unpack2(w4.z, lo, hi); oa[u*8+4] = fmaf(pj, lo, oa[u*8+4]); oa[u*8+5] = fmaf(pj, hi, oa[u*8+5]);
        unpack2(w4.w, lo, hi); oa[u*8+6] = fmaf(pj, lo, oa[u*8+6]); oa[u*8+7] = fmaf(pj, hi, oa[u*8+7]);
      }
    }
    uint4 ov[3];
    #pragma unroll
    for (int u = 0; u < 3; ++u) {
      ov[u].x = pk2(oa[u*8+0], oa[u*8+1]);
      ov[u].y = pk2(oa[u*8+2], oa[u*8+3]);
      ov[u].z = pk2(oa[u*8+4], oa[u*8+5]);
      ov[u].w = pk2(oa[u*8+6], oa[u*8+7]);
    }
    uint4* op = (uint4*)(r1 + aqrow * 200 + ah * 48 + ad0);
    #pragma unroll
    for (int u = 0; u < 3; ++u) op[u] = ov[u];
  }
  __syncthreads();

  // G2: A = O @ w_out + b_out -> r2 cols 192..384 (over dead K) + packed regs for G4
  uint2 areg[3][2];
  gemm_stage<3, 6>(r1, 200, wo_t, wave * 3, 6, lr, kg,
    [&](int nt, f32x4 (&acc)[2]) {
      int n0 = (wave * 3 + nt) * 16 + kg * 4;
      float4 bo = *(const float4*)(b_out + n0);
      #pragma unroll
      for (int m = 0; m < 2; ++m) {
        uint2 u;
        u.x = pk2(acc[m][0] + bo.x, acc[m][1] + bo.y);
        u.y = pk2(acc[m][2] + bo.z, acc[m][3] + bo.w);
        areg[nt][m] = u;
        *(uint2*)(r2 + (m * 16 + lr) * 392 + 192 + n0) = u;
      }
    });
  __syncthreads();

  // LN2: (x + A) -> r1 (normed2; O dead)
  layernorm_pass<true>(xg, r2, r1, g2, b2, t);
  __syncthreads();

  // G3: h1 = gelu(normed2 @ w_f1 + b_f1) -> r2 stride 392, cols 0..384 (V,A dead)
  gemm_stage<6, 6>(r1, 200, wf1_t, wave * 6, 6, lr, kg,
    [&](int nt, f32x4 (&acc)[2]) {
      int n0 = (wave * 6 + nt) * 16 + kg * 4;
      float4 bf = *(const float4*)(b_f1 + n0);
      #pragma unroll
      for (int m = 0; m < 2; ++m) {
        float ge[4];
        #pragma unroll
        for (int i = 0; i < 4; ++i)
          ge[i] = gelu_fast(acc[m][i] + ((const float*)&bf)[i]);
        uint2 u; u.x = pk2(ge[0], ge[1]); u.y = pk2(ge[2], ge[3]);
        *(uint2*)(r2 + (m * 16 + lr) * 392 + n0) = u;
      }
    });
  __syncthreads();

  // G4: out = x + A + h1 @ w_f2 + b_f2  (K=384, kc-outer, dbuf af+bv)
  {
    f32x4 acc[3][2] = {};
    bf16x8 afb[2][2], bvb[2][3];
    #pragma unroll
    for (int m = 0; m < 2; ++m)
      afb[0][m] = *(const bf16x8*)(r2 + (m * 16 + lr) * 392 + kg * 8);
    #pragma unroll
    for (int nt = 0; nt < 3; ++nt)
      bvb[0][nt] = *(const bf16x8*)(wf2_t + (size_t)((wave * 3 + nt) * 12) * 512 + lr * 32 + kg * 8);
    #pragma unroll
    for (int kc = 0; kc < 12; ++kc) {
      if (kc + 1 < 12) {
        #pragma unroll
        for (int m = 0; m < 2; ++m)
          afb[(kc + 1) & 1][m] =
              *(const bf16x8*)(r2 + (m * 16 + lr) * 392 + (kc + 1) * 32 + kg * 8);
        #pragma unroll
        for (int nt = 0; nt < 3; ++nt)
          bvb[(kc + 1) & 1][nt] =
              *(const bf16x8*)(wf2_t + (size_t)((wave * 3 + nt) * 12 + kc + 1) * 512 + lr * 32 + kg * 8);
      }
      #pragma unroll
      for (int nt = 0; nt < 3; ++nt)
        #pragma unroll
        for (int m = 0; m < 2; ++m)
          acc[nt][m] = __builtin_amdgcn_mfma_f32_16x16x32_bf16(bvb[kc & 1][nt], afb[kc & 1][m], acc[nt][m], 0, 0, 0);
    }
    #pragma unroll
    for (int nt = 0; nt < 3; ++nt) {
      int n0 = (wave * 3 + nt) * 16 + kg * 4;
      float4 bf = *(const float4*)(b_f2 + n0);
      #pragma unroll
      for (int m = 0; m < 2; ++m) {
        int row = m * 16 + lr;
        float4 xv = *(const float4*)(xg + (size_t)row * 192 + n0);
        float a0, a1, a2f, a3;
        unpack2(areg[nt][m].x, a0, a1); unpack2(areg[nt][m].y, a2f, a3);
        float4 o;
        o.x = xv.x + a0  + acc[nt][m][0] + bf.x;
        o.y = xv.y + a1  + acc[nt][m][1] + bf.y;
        o.z = xv.z + a2f + acc[nt][m][2] + bf.z;
        o.w = xv.w + a3  + acc[nt][m][3] + bf.w;
        *(float4*)(og + (size_t)row * 192 + n0) = o;
      }
    }
  }
}

extern "C" void kernel_launch(void* const* d_in, const int* in_sizes, int n_in,
                              void* d_out, int out_size, void* d_ws, size_t ws_size,
                              hipStream_t stream) {
  const float* x   = (const float*)d_in[0];
  const float* wq  = (const float*)d_in[1];
  const float* wo  = (const float*)d_in[2];
  const float* bo  = (const float*)d_in[3];
  const float* g1  = (const float*)d_in[4];
  const float* b1  = (const float*)d_in[5];
  const float* g2  = (const float*)d_in[6];
  const float* b2  = (const float*)d_in[7];
  const float* wf1 = (const float*)d_in[8];
  const float* bf1 = (const float*)d_in[9];
  const float* wf2 = (const float*)d_in[10];
  const float* bf2 = (const float*)d_in[11];
  unsigned short* wsb = (unsigned short*)d_ws;  // needs 589824 B

  pack_weights<<<1152, 256, 0, stream>>>(wq, wo, wf1, wf2, wsb);

  int tokens = in_sizes[0] / 192;   // 262144
  int nb = tokens / 32;             // 8192
  fused_block<<<nb, 256, 0, stream>>>(x, g1, b1, g2, b2, bo, bf1, bf2,
      wsb, wsb + 110592, wsb + 147456, wsb + 221184, (float*)d_out);
}

// Round 5
// 376.204 us; speedup vs baseline: 1.3733x; 1.3733x over previous
//
#include <hip/hip_runtime.h>
#include <hip/hip_bf16.h>

typedef __bf16 bf16x8 __attribute__((ext_vector_type(8)));
typedef float f32x4 __attribute__((ext_vector_type(4)));

#define DEV static __device__ __forceinline__

DEV unsigned short f2b(float f) {
  return __builtin_bit_cast(unsigned short, __float2bfloat16(f));
}
DEV unsigned pk2(float a, float b) {
  return (unsigned)f2b(a) | ((unsigned)f2b(b) << 16);
}
DEV void unpack2(unsigned u, float& lo, float& hi) {
  lo = __uint_as_float(u << 16);
  hi = __uint_as_float(u & 0xffff0000u);
}
// tanh-form gelu: h*e/(e+1), e = exp(2*sqrt(2/pi)*(h+0.044715h^3)).
// Written as h - h*rcp(e+1): exact at both saturation ends (e->inf => h, e->0 => 0).
DEV float gelu_fast(float h) {
  float u = h * (1.5957691216f + 0.0713554f * h * h);
  float e = __expf(u);
  float r = __builtin_amdgcn_rcpf(e + 1.f);
  return h - h * r;
}

// ---- weight packing: src [k][n] fp32 -> fragment-native bf16 layout ----
// dst[((ntile*KC + kc)*512) + nl*32 + kgl] for n = ntile*16+nl, k = kc*32+kgl.
// A wave's (ntile,kc) fragment load = 64 lanes x 16B = contiguous 1KB.
// ws element offsets: wq@0 (110592) wo@110592 (36864) wf1@147456 (73728) wf2@221184 (73728)
__global__ void pack_weights(const float* __restrict__ wq,
                             const float* __restrict__ wo,
                             const float* __restrict__ wf1,
                             const float* __restrict__ wf2,
                             unsigned short* __restrict__ ws) {
  int i = blockIdx.x * 256 + threadIdx.x;  // grid covers exactly 294912
  const float* src; int j, N, KC;
  if (i < 110592)      { j = i;          src = wq;  N = 576; KC = 6; }
  else if (i < 147456) { j = i - 110592; src = wo;  N = 192; KC = 6; }
  else if (i < 221184) { j = i - 147456; src = wf1; N = 384; KC = 6; }
  else                 { j = i - 221184; src = wf2; N = 192; KC = 12; }
  int tk = j >> 9, r = j & 511;
  int nt = tk / KC, kc = tk % KC;
  int n = nt * 16 + (r >> 5), k = kc * 32 + (r & 31);
  ws[i] = f2b(src[k * N + n]);
}

// GEMM stage, swapped operands: mfma(b_frag, a_frag).
// Thread (lr,kg): C[token = m*16+lr][n = (nt0+nt)*16 + kg*4 .. +3].
// A: LDS bf16 [32 x K] stride astride. Bp: packed global bf16 (layout above).
// B fragments double-buffered: nt+1's loads issue before nt's MFMAs.
template<int NT, int KC, typename EPI>
DEV void gemm_stage(const unsigned short* As, int astride,
                    const unsigned short* Bp, int nt0, int KCtot,
                    int lr, int kg, EPI epi) {
  bf16x8 af[2][KC];
  #pragma unroll
  for (int m = 0; m < 2; ++m)
    #pragma unroll
    for (int kc = 0; kc < KC; ++kc)
      af[m][kc] = *(const bf16x8*)(As + (m * 16 + lr) * astride + kc * 32 + kg * 8);
  const unsigned short* bb = Bp + lr * 32 + kg * 8;
  bf16x8 bbuf[2][KC];
  #pragma unroll
  for (int kc = 0; kc < KC; ++kc)
    bbuf[0][kc] = *(const bf16x8*)(bb + (size_t)(nt0 * KCtot + kc) * 512);
  #pragma unroll
  for (int nt = 0; nt < NT; ++nt) {
    if (nt + 1 < NT) {
      #pragma unroll
      for (int kc = 0; kc < KC; ++kc)
        bbuf[(nt + 1) & 1][kc] =
            *(const bf16x8*)(bb + (size_t)((nt0 + nt + 1) * KCtot + kc) * 512);
    }
    f32x4 acc[2] = {};
    #pragma unroll
    for (int kc = 0; kc < KC; ++kc)
      #pragma unroll
      for (int m = 0; m < 2; ++m)
        acc[m] = __builtin_amdgcn_mfma_f32_16x16x32_bf16(bbuf[nt & 1][kc], af[m][kc], acc[m], 0, 0, 0);
    epi(nt, acc);
  }
}

// LayerNorm over 32 rows: src = x (global, row stride 192) [+ A (LDS bf16, stride 392, col off 192)].
// dst = LDS bf16 stride 200. thread t: row = t>>3, eighth = t&7 (24 elems).
// Two-pass variance (matches reference mean((x-mu)^2) ordering).
template<bool ADD_A>
DEV void layernorm_pass(const float* __restrict__ xg, const unsigned short* Abuf,
                        unsigned short* dst,
                        const float* __restrict__ gg, const float* __restrict__ bb,
                        int t) {
  int r = t >> 3, q = t & 7;
  float vals[24];
  float s = 0.f;
  #pragma unroll
  for (int j = 0; j < 6; ++j) {
    float4 v = *(const float4*)(xg + (size_t)r * 192 + q * 24 + j * 4);
    if (ADD_A) {
      uint2 a2 = *(const uint2*)(Abuf + r * 392 + 192 + q * 24 + j * 4);
      float a0, a1, a2f, a3;
      unpack2(a2.x, a0, a1); unpack2(a2.y, a2f, a3);
      v.x += a0; v.y += a1; v.z += a2f; v.w += a3;
    }
    vals[j*4+0] = v.x; vals[j*4+1] = v.y; vals[j*4+2] = v.z; vals[j*4+3] = v.w;
    s += v.x + v.y + v.z + v.w;
  }
  s += __shfl_xor(s, 1); s += __shfl_xor(s, 2); s += __shfl_xor(s, 4);
  float mu = s * (1.f / 192.f);
  float ss = 0.f;
  #pragma unroll
  for (int i = 0; i < 24; ++i) { float d = vals[i] - mu; ss += d * d; }
  ss += __shfl_xor(ss, 1); ss += __shfl_xor(ss, 2); ss += __shfl_xor(ss, 4);
  float rstd = rsqrtf(ss * (1.f / 192.f) + 1e-5f);
  #pragma unroll
  for (int j = 0; j < 6; ++j) {
    int c = q * 24 + j * 4;
    float4 g4 = *(const float4*)(gg + c);
    float4 b4 = *(const float4*)(bb + c);
    uint2 u;
    u.x = pk2((vals[j*4+0] - mu) * rstd * g4.x + b4.x,
              (vals[j*4+1] - mu) * rstd * g4.y + b4.y);
    u.y = pk2((vals[j*4+2] - mu) * rstd * g4.z + b4.z,
              (vals[j*4+3] - mu) * rstd * g4.w + b4.w);
    *(uint2*)(dst + r * 200 + c) = u;
  }
}

// Fused transformer block: 4 batches (32 rows) per workgroup, 256 threads (4 waves).
// LDS: r1 bf16 32x200 (12800B: normed1 -> attnO -> normed2)
//      r2 bf16 32x392 (25088B): [Q 0..192 | K 192..384] -> [V 0..192 | A 192..384] -> h1 0..384
// total 37888B -> 4 blocks/CU by LDS. launch_bounds min=3 (NOT 4: min=4 capped VGPR
// at 64 and spilled ~1.1GB/dispatch to scratch, dur 394->516us). With ~100 VGPR <= 128
// the HW can still schedule 4 blocks/CU.
__global__ __launch_bounds__(256, 3)
void fused_block(const float* __restrict__ x,
                 const float* __restrict__ g1, const float* __restrict__ b1,
                 const float* __restrict__ g2, const float* __restrict__ b2,
                 const float* __restrict__ b_out, const float* __restrict__ b_f1,
                 const float* __restrict__ b_f2,
                 const unsigned short* __restrict__ wq_t,
                 const unsigned short* __restrict__ wo_t,
                 const unsigned short* __restrict__ wf1_t,
                 const unsigned short* __restrict__ wf2_t,
                 float* __restrict__ out)
{
  __shared__ __align__(16) unsigned short r1[32 * 200];
  __shared__ __align__(16) unsigned short r2[32 * 392];

  const int t = threadIdx.x;
  const int wave = t >> 6;
  const int lane = t & 63;
  const int lr = lane & 15;
  const int kg = lane >> 4;
  const int token0 = blockIdx.x * 32;
  const float* xg = x + (size_t)token0 * 192;
  float* og = out + (size_t)token0 * 192;

  // LN1: x (global) -> r1 (normed1, bf16)
  layernorm_pass<false>(xg, nullptr, r1, g1, b1, t);
  __syncthreads();

  // G1a: Q,K = normed1 @ w_qkv[:, :384]  (24 nt, wave owns 6) -> r2 stride 392
  gemm_stage<6, 6>(r1, 200, wq_t, wave * 6, 6, lr, kg,
    [&](int nt, f32x4 (&acc)[2]) {
      int n0 = (wave * 6 + nt) * 16 + kg * 4;
      #pragma unroll
      for (int m = 0; m < 2; ++m) {
        uint2 u; u.x = pk2(acc[m][0], acc[m][1]); u.y = pk2(acc[m][2], acc[m][3]);
        *(uint2*)(r2 + (m * 16 + lr) * 392 + n0) = u;
      }
    });
  __syncthreads();

  // attention scores: 16 (batch,head) groups x 8 q-rows x 2 d-halves.
  const int ag = t >> 4, aqi = (t >> 1) & 7, ahalf = t & 1;
  const int abl = ag >> 2, ah = ag & 3;
  const int aqrow = abl * 8 + aqi;
  const int ad0 = ahalf * 24;
  float p[8];
  {
    float qv[24];
    const uint4* qp = (const uint4*)(r2 + aqrow * 392 + ah * 48 + ad0);
    #pragma unroll
    for (int u = 0; u < 3; ++u) {
      uint4 w4 = qp[u];
      unpack2(w4.x, qv[u*8+0], qv[u*8+1]);
      unpack2(w4.y, qv[u*8+2], qv[u*8+3]);
      unpack2(w4.z, qv[u*8+4], qv[u*8+5]);
      unpack2(w4.w, qv[u*8+6], qv[u*8+7]);
    }
    #pragma unroll
    for (int j = 0; j < 8; ++j) {
      const uint4* kp = (const uint4*)(r2 + (abl * 8 + j) * 392 + 192 + ah * 48 + ad0);
      float d = 0.f;
      #pragma unroll
      for (int u = 0; u < 3; ++u) {
        uint4 w4 = kp[u];
        float lo, hi;
        unpack2(w4.x, lo, hi); d = fmaf(lo, qv[u*8+0], d); d = fmaf(hi, qv[u*8+1], d);
        unpack2(w4.y, lo, hi); d = fmaf(lo, qv[u*8+2], d); d = fmaf(hi, qv[u*8+3], d);
        unpack2(w4.z, lo, hi); d = fmaf(lo, qv[u*8+4], d); d = fmaf(hi, qv[u*8+5], d);
        unpack2(w4.w, lo, hi); d = fmaf(lo, qv[u*8+6], d); d = fmaf(hi, qv[u*8+7], d);
      }
      d += __shfl_xor(d, 1);             // combine the two d-halves
      p[j] = d * 0.14433756729740643f;   // 1/sqrt(48)
    }
    float mx = p[0];
    #pragma unroll
    for (int j = 1; j < 8; ++j) mx = fmaxf(mx, p[j]);
    float sum = 0.f;
    #pragma unroll
    for (int j = 0; j < 8; ++j) { p[j] = __expf(p[j] - mx); sum += p[j]; }
    float inv = 1.f / sum;
    #pragma unroll
    for (int j = 0; j < 8; ++j) p[j] *= inv;
  }
  __syncthreads();   // all Q/K reads done before V overwrites Q

  // G1b: V = normed1 @ w_qkv[:, 384:]  (nt 24..35, wave owns 3) -> r2 cols 0..191
  gemm_stage<3, 6>(r1, 200, wq_t, 24 + wave * 3, 6, lr, kg,
    [&](int nt, f32x4 (&acc)[2]) {
      int n0 = (wave * 3 + nt) * 16 + kg * 4;
      #pragma unroll
      for (int m = 0; m < 2; ++m) {
        uint2 u; u.x = pk2(acc[m][0], acc[m][1]); u.y = pk2(acc[m][2], acc[m][3]);
        *(uint2*)(r2 + (m * 16 + lr) * 392 + n0) = u;
      }
    });
  __syncthreads();

  // PV: O[q][d] = sum_j p[j] V[j][d]  -> r1 (overwrites normed1)
  {
    float oa[24];
    #pragma unroll
    for (int e = 0; e < 24; ++e) oa[e] = 0.f;
    #pragma unroll
    for (int j = 0; j < 8; ++j) {
      float pj = p[j];
      const uint4* vp = (const uint4*)(r2 + (abl * 8 + j) * 392 + ah * 48 + ad0);
      #pragma unroll
      for (int u = 0; u < 3; ++u) {
        uint4 w4 = vp[u];
        float lo, hi;
        unpack2(w4.x, lo, hi); oa[u*8+0] = fmaf(pj, lo, oa[u*8+0]); oa[u*8+1] = fmaf(pj, hi, oa[u*8+1]);
        unpack2(w4.y, lo, hi); oa[u*8+2] = fmaf(pj, lo, oa[u*8+2]); oa[u*8+3] = fmaf(pj, hi, oa[u*8+3]);
        unpack2(w4.z, lo, hi); oa[u*8+4] = fmaf(pj, lo, oa[u*8+4]); oa[u*8+5] = fmaf(pj, hi, oa[u*8+5]);
        unpack2(w4.w, lo, hi); oa[u*8+6] = fmaf(pj, lo, oa[u*8+6]); oa[u*8+7] = fmaf(pj, hi, oa[u*8+7]);
      }
    }
    uint4 ov[3];
    #pragma unroll
    for (int u = 0; u < 3; ++u) {
      ov[u].x = pk2(oa[u*8+0], oa[u*8+1]);
      ov[u].y = pk2(oa[u*8+2], oa[u*8+3]);
      ov[u].z = pk2(oa[u*8+4], oa[u*8+5]);
      ov[u].w = pk2(oa[u*8+6], oa[u*8+7]);
    }
    uint4* op = (uint4*)(r1 + aqrow * 200 + ah * 48 + ad0);
    #pragma unroll
    for (int u = 0; u < 3; ++u) op[u] = ov[u];
  }
  __syncthreads();

  // G2: A = O @ w_out + b_out -> r2 cols 192..384 (over dead K) + packed regs for G4
  uint2 areg[3][2];
  gemm_stage<3, 6>(r1, 200, wo_t, wave * 3, 6, lr, kg,
    [&](int nt, f32x4 (&acc)[2]) {
      int n0 = (wave * 3 + nt) * 16 + kg * 4;
      float4 bo = *(const float4*)(b_out + n0);
      #pragma unroll
      for (int m = 0; m < 2; ++m) {
        uint2 u;
        u.x = pk2(acc[m][0] + bo.x, acc[m][1] + bo.y);
        u.y = pk2(acc[m][2] + bo.z, acc[m][3] + bo.w);
        areg[nt][m] = u;
        *(uint2*)(r2 + (m * 16 + lr) * 392 + 192 + n0) = u;
      }
    });
  __syncthreads();

  // LN2: (x + A) -> r1 (normed2; O dead)
  layernorm_pass<true>(xg, r2, r1, g2, b2, t);
  __syncthreads();

  // G3: h1 = gelu(normed2 @ w_f1 + b_f1) -> r2 stride 392, cols 0..384 (V,A dead)
  gemm_stage<6, 6>(r1, 200, wf1_t, wave * 6, 6, lr, kg,
    [&](int nt, f32x4 (&acc)[2]) {
      int n0 = (wave * 6 + nt) * 16 + kg * 4;
      float4 bf = *(const float4*)(b_f1 + n0);
      #pragma unroll
      for (int m = 0; m < 2; ++m) {
        float ge[4];
        #pragma unroll
        for (int i = 0; i < 4; ++i)
          ge[i] = gelu_fast(acc[m][i] + ((const float*)&bf)[i]);
        uint2 u; u.x = pk2(ge[0], ge[1]); u.y = pk2(ge[2], ge[3]);
        *(uint2*)(r2 + (m * 16 + lr) * 392 + n0) = u;
      }
    });
  __syncthreads();

  // G4: out = x + A + h1 @ w_f2 + b_f2  (K=384, kc-outer, dbuf af+bv)
  {
    f32x4 acc[3][2] = {};
    bf16x8 afb[2][2], bvb[2][3];
    #pragma unroll
    for (int m = 0; m < 2; ++m)
      afb[0][m] = *(const bf16x8*)(r2 + (m * 16 + lr) * 392 + kg * 8);
    #pragma unroll
    for (int nt = 0; nt < 3; ++nt)
      bvb[0][nt] = *(const bf16x8*)(wf2_t + (size_t)((wave * 3 + nt) * 12) * 512 + lr * 32 + kg * 8);
    #pragma unroll
    for (int kc = 0; kc < 12; ++kc) {
      if (kc + 1 < 12) {
        #pragma unroll
        for (int m = 0; m < 2; ++m)
          afb[(kc + 1) & 1][m] =
              *(const bf16x8*)(r2 + (m * 16 + lr) * 392 + (kc + 1) * 32 + kg * 8);
        #pragma unroll
        for (int nt = 0; nt < 3; ++nt)
          bvb[(kc + 1) & 1][nt] =
              *(const bf16x8*)(wf2_t + (size_t)((wave * 3 + nt) * 12 + kc + 1) * 512 + lr * 32 + kg * 8);
      }
      #pragma unroll
      for (int nt = 0; nt < 3; ++nt)
        #pragma unroll
        for (int m = 0; m < 2; ++m)
          acc[nt][m] = __builtin_amdgcn_mfma_f32_16x16x32_bf16(bvb[kc & 1][nt], afb[kc & 1][m], acc[nt][m], 0, 0, 0);
    }
    #pragma unroll
    for (int nt = 0; nt < 3; ++nt) {
      int n0 = (wave * 3 + nt) * 16 + kg * 4;
      float4 bf = *(const float4*)(b_f2 + n0);
      #pragma unroll
      for (int m = 0; m < 2; ++m) {
        int row = m * 16 + lr;
        float4 xv = *(const float4*)(xg + (size_t)row * 192 + n0);
        float a0, a1, a2f, a3;
        unpack2(areg[nt][m].x, a0, a1); unpack2(areg[nt][m].y, a2f, a3);
        float4 o;
        o.x = xv.x + a0  + acc[nt][m][0] + bf.x;
        o.y = xv.y + a1  + acc[nt][m][1] + bf.y;
        o.z = xv.z + a2f + acc[nt][m][2] + bf.z;
        o.w = xv.w + a3  + acc[nt][m][3] + bf.w;
        *(float4*)(og + (size_t)row * 192 + n0) = o;
      }
    }
  }
}

extern "C" void kernel_launch(void* const* d_in, const int* in_sizes, int n_in,
                              void* d_out, int out_size, void* d_ws, size_t ws_size,
                              hipStream_t stream) {
  const float* x   = (const float*)d_in[0];
  const float* wq  = (const float*)d_in[1];
  const float* wo  = (const float*)d_in[2];
  const float* bo  = (const float*)d_in[3];
  const float* g1  = (const float*)d_in[4];
  const float* b1  = (const float*)d_in[5];
  const float* g2  = (const float*)d_in[6];
  const float* b2  = (const float*)d_in[7];
  const float* wf1 = (const float*)d_in[8];
  const float* bf1 = (const float*)d_in[9];
  const float* wf2 = (const float*)d_in[10];
  const float* bf2 = (const float*)d_in[11];
  unsigned short* wsb = (unsigned short*)d_ws;  // needs 589824 B

  pack_weights<<<1152, 256, 0, stream>>>(wq, wo, wf1, wf2, wsb);

  int tokens = in_sizes[0] / 192;   // 262144
  int nb = tokens / 32;             // 8192
  fused_block<<<nb, 256, 0, stream>>>(x, g1, b1, g2, b2, bo, bf1, bf2,
      wsb, wsb + 110592, wsb + 147456, wsb + 221184, (float*)d_out);
}